// Round 2
// baseline (377.918 us; speedup 1.0000x reference)
//
#include <hip/hip_runtime.h>
#include <math.h>

#define DFEAT 128

// One block per anchor. segment_ids are sorted, so anchor a's rows are the
// contiguous range [lower_bound(a), lower_bound(a+1)). Block = 256 threads =
// 16 groups x 16 lanes; group g handles rows start+g, start+g+16, ...
// Each lane holds 8 anchor floats in registers; a wave's 4 groups read 4
// consecutive rows = 2 KB fully-coalesced per iteration.
// Entire result (log1p of per-anchor sum, scaled) accumulates into d_out via
// one float atomicAdd per block -- no workspace, no second kernel.
__global__ __launch_bounds__(256) void icc_fused_kernel(
    const float* __restrict__ anchors,
    const float* __restrict__ Xn,
    const int*   __restrict__ seg,
    float*       __restrict__ out,
    int total, float inv_total)
{
    const int a   = blockIdx.x;        // anchor id
    const int tid = threadIdx.x;
    const int gid = tid >> 4;          // 16-lane group id, 0..15
    const int lr  = tid & 15;          // lane within group

    // Binary search for [start, end) of this anchor's segment.
    // Uniform across the block: same-address loads broadcast.
    int lo = 0, hi = total;
    while (lo < hi) {
        const int mid = (lo + hi) >> 1;
        if (seg[mid] < a) lo = mid + 1; else hi = mid;
    }
    const int start = lo;
    hi = total;
    while (lo < hi) {
        const int mid = (lo + hi) >> 1;
        if (seg[mid] < a + 1) lo = mid + 1; else hi = mid;
    }
    const int end = lo;

    const float eps = 1e-4f / (float)DFEAT;

    // Anchor fragment in registers: lane lr owns cols [8*lr, 8*lr+8).
    const float* ap = anchors + (size_t)a * DFEAT + lr * 8;
    const float4 av0 = *reinterpret_cast<const float4*>(ap);
    const float4 av1 = *reinterpret_cast<const float4*>(ap + 4);

    float run = 0.0f;
    for (int r = start + gid; r < end; r += 16) {
        const float* xp = Xn + (size_t)r * DFEAT + lr * 8;
        const float4 x0 = *reinterpret_cast<const float4*>(xp);
        const float4 x1 = *reinterpret_cast<const float4*>(xp + 4);
        float d, sq;
        d = x0.x - av0.x; sq  = d * d;
        d = x0.y - av0.y; sq += d * d;
        d = x0.z - av0.z; sq += d * d;
        d = x0.w - av0.w; sq += d * d;
        d = x1.x - av1.x; sq += d * d;
        d = x1.y - av1.y; sq += d * d;
        d = x1.z - av1.z; sq += d * d;
        d = x1.w - av1.w; sq += d * d;
        #pragma unroll
        for (int off = 8; off > 0; off >>= 1)   // xor <= 15 stays in the group
            sq += __shfl_xor(sq, off);
        run += sqrtf(sq + eps);                  // replicated across group
    }

    // Block reduce of the 16 group sums, then one atomic per block.
    __shared__ float gsum[16];
    if (lr == 0) gsum[gid] = run;
    __syncthreads();
    if (tid == 0) {
        float s = 0.0f;
        #pragma unroll
        for (int i = 0; i < 16; ++i) s += gsum[i];
        atomicAdd(out, log1pf(s) * inv_total);
    }
}

extern "C" void kernel_launch(void* const* d_in, const int* in_sizes, int n_in,
                              void* d_out, int out_size, void* d_ws, size_t ws_size,
                              hipStream_t stream) {
    const float* anchors = (const float*)d_in[0];
    const float* Xn      = (const float*)d_in[1];
    const int*   seg     = (const int*)d_in[2];
    float* out = (float*)d_out;

    const int num_anchors = in_sizes[0] / DFEAT;   // 1024
    const int total       = in_sizes[2];           // 524288

    hipMemsetAsync(out, 0, sizeof(float), stream); // 4-byte fill, ~us
    icc_fused_kernel<<<num_anchors, 256, 0, stream>>>(
        anchors, Xn, seg, out, total, 1.0f / (float)total);
}

// Round 3
// 362.220 us; speedup vs baseline: 1.0433x; 1.0433x over previous
//
#include <hip/hip_runtime.h>
#include <math.h>

#define DFEAT 128
#define A_MAX 1024
#define ROWS_PER_BLOCK 64

// Each half-wave (32 lanes) handles one row: lane l loads float4 at col 4*l.
// A full 64-lane wave therefore reads 2 contiguous rows = 1 KiB coalesced.
// Sorted segment_ids => each 64-row block touches only anchors
// [seg[rowBase], seg[lastRow]] (~1-3 entries): init/flush only that range.
__global__ __launch_bounds__(256) void icc_dist_kernel(
    const float* __restrict__ anchors,
    const float* __restrict__ Xn,
    const int*   __restrict__ seg,
    float*       __restrict__ per_anchor,  // [num_anchors] global accumulator
    int total, int num_anchors)
{
    __shared__ float acc[A_MAX];
    const int tid = threadIdx.x;
    const int rowBase = blockIdx.x * ROWS_PER_BLOCK;
    const int lastRow = min(rowBase + ROWS_PER_BLOCK - 1, total - 1);
    const int aLo = seg[rowBase];          // uniform -> broadcast load
    const int aHi = seg[lastRow];
    for (int i = aLo + tid; i <= aHi; i += 256) acc[i] = 0.0f;
    __syncthreads();

    const int lane = tid & 31;   // lane within half-wave
    const int hw   = tid >> 5;   // half-wave id within block (0..7)
    const float eps = 1e-4f / (float)DFEAT;

    #pragma unroll
    for (int r = 0; r < ROWS_PER_BLOCK / 8; ++r) {
        const int row = rowBase + r * 8 + hw;
        if (row < total) {
            const int a = seg[row];  // 32 lanes same addr -> broadcast load
            const float4 x  = *reinterpret_cast<const float4*>(
                Xn + (size_t)row * DFEAT + lane * 4);
            const float4 av = *reinterpret_cast<const float4*>(
                anchors + (size_t)a * DFEAT + lane * 4);
            const float dx = x.x - av.x;
            const float dy = x.y - av.y;
            const float dz = x.z - av.z;
            const float dw = x.w - av.w;
            float sq = dx * dx + dy * dy + dz * dz + dw * dw;
            #pragma unroll
            for (int off = 16; off > 0; off >>= 1)
                sq += __shfl_down(sq, off, 32);
            if (lane == 0) {
                const float dist = sqrtf(sq + eps);
                atomicAdd(&acc[a], dist);            // LDS atomic, in-range
            }
        }
    }
    __syncthreads();
    // Flush block-local sums for the touched anchor range only.
    for (int i = aLo + tid; i <= aHi; i += 256) {
        const float v = acc[i];
        if (v != 0.0f) atomicAdd(&per_anchor[i], v);
    }
}

__global__ __launch_bounds__(256) void icc_final_kernel(
    const float* __restrict__ per_anchor,
    float*       __restrict__ out,
    int num_anchors, float inv_total)
{
    __shared__ float red[4];
    const int tid = threadIdx.x;
    float s = 0.0f;
    for (int i = tid; i < num_anchors; i += 256)
        s += log1pf(per_anchor[i]);
    #pragma unroll
    for (int off = 32; off > 0; off >>= 1)
        s += __shfl_down(s, off, 64);
    if ((tid & 63) == 0) red[tid >> 6] = s;
    __syncthreads();
    if (tid == 0) {
        const float t = red[0] + red[1] + red[2] + red[3];
        out[0] = t * inv_total;
    }
}

extern "C" void kernel_launch(void* const* d_in, const int* in_sizes, int n_in,
                              void* d_out, int out_size, void* d_ws, size_t ws_size,
                              hipStream_t stream) {
    const float* anchors = (const float*)d_in[0];
    const float* Xn      = (const float*)d_in[1];
    const int*   seg     = (const int*)d_in[2];
    float* out = (float*)d_out;

    const int num_anchors = in_sizes[0] / DFEAT;   // 1024
    const int total       = in_sizes[2];           // 524288

    float* per_anchor = (float*)d_ws;              // num_anchors floats
    hipMemsetAsync(per_anchor, 0, (size_t)num_anchors * sizeof(float), stream);

    const int blocks = (total + ROWS_PER_BLOCK - 1) / ROWS_PER_BLOCK;
    icc_dist_kernel<<<blocks, 256, 0, stream>>>(
        anchors, Xn, seg, per_anchor, total, num_anchors);
    icc_final_kernel<<<1, 256, 0, stream>>>(
        per_anchor, out, num_anchors, 1.0f / (float)total);
}